// Round 16
// baseline (6004.956 us; speedup 1.0000x reference)
//
#include <hip/hip_runtime.h>
#include <hip/hip_bf16.h>
#include <cstdint>
#include <cstddef>

typedef unsigned short ushort_t;
typedef __attribute__((ext_vector_type(8))) __bf16 bf16x8;
typedef __attribute__((ext_vector_type(4))) float f32x4;
typedef __attribute__((ext_vector_type(4))) unsigned short us4;

__device__ __forceinline__ unsigned short f2bf(float f) {
    union { __hip_bfloat16 h; unsigned short u; } v;
    v.h = __float2bfloat16(f);
    return v.u;
}
__device__ __forceinline__ float bf2f(unsigned short u) {
    union { unsigned int i; float f; } v;
    v.i = ((unsigned int)u) << 16;
    return v.f;
}

__device__ __forceinline__ void gload16(const void* g, void* l) {
    __builtin_amdgcn_global_load_lds((const __attribute__((address_space(1))) void*)g,
                                     (__attribute__((address_space(3))) void*)l,
                                     16, 0, 0);
}

#define BARRIER() asm volatile("s_barrier" ::: "memory")

#define MMX(ACC, QM, AV, BV) do {                                                \
    _Pragma("unroll") for (int mi = 0; mi < 4; ++mi)                             \
    _Pragma("unroll") for (int ni = 0; ni < 4; ++ni)                             \
        ACC[(QM) * 4 + mi][ni] = __builtin_amdgcn_mfma_f32_16x16x32_bf16(        \
            AV[mi], BV[ni], ACC[(QM) * 4 + mi][ni], 0, 0, 0);                    \
} while (0)

#define TILE_SYNC() do {                                                         \
    __builtin_amdgcn_sched_barrier(0);                                           \
    asm volatile("s_waitcnt lgkmcnt(0) vmcnt(0)" ::: "memory");                  \
    __builtin_amdgcn_sched_barrier(0);                                           \
    BARRIER();                                                                   \
} while (0)

// ---------------------------------------------------------------------------
// 256x256 GEMM, BK=64, register-pipelined (r15/session-best): C = A @ Bt^T.
// 512 threads = 8 waves (2M x 4N), per-wave 128x64 output. Static LDS 128 KB
// (epilogue reduce aliased into tile LDS). ONE fortified sync per tile.
// EPI: 0 bias+relu, 1 exp (+rowsum AND colsum partials), 3 relu+colsum.
// ---------------------------------------------------------------------------
template<int EPI>
__global__ __launch_bounds__(512) void gemm256(
        const ushort_t* __restrict__ A, const ushort_t* __restrict__ Bt,
        ushort_t* __restrict__ C, int M, int N, int K,
        const float* __restrict__ epi_vec, float* __restrict__ rowp,
        float* __restrict__ colp)
{
    __shared__ __align__(16) ushort_t lds[65536];   // 128KB
    float* redp    = (float*)lds;
    float* rowredp = (float*)(lds + 1024);

    const int nN = N >> 8;
    const int nwg = (int)gridDim.x;
    const int orig = (int)blockIdx.x;
    const int q = nwg >> 3, r = nwg & 7, xcd = orig & 7;
    const int wgid = (xcd < r ? xcd * (q + 1) : r * (q + 1) + (xcd - r) * q) + (orig >> 3);
    const int mb = wgid / nN, nb = wgid % nN;

    const int t = (int)threadIdx.x;
    const int lane = t & 63;
    const int wave = t >> 6;
    const int wm = wave >> 2;
    const int wn = wave & 3;
    const int fr = lane & 15;
    const int fk = lane >> 4;

    const int NT = K >> 6;

    const int l8 = lane >> 3;
    const int lcc = ((lane & 7) ^ (l8 & 7)) * 8;
    const ushort_t* gA = A + (size_t)(mb * 256 + wave * 8 + l8) * (size_t)K + lcc;
    const ushort_t* gB = Bt + (size_t)(nb * 256 + wave * 8 + l8) * (size_t)K + lcc;

    auto stage1 = [&](int op, int dd, int h, int j, int T2) {
        const ushort_t* g = (op ? gB : gA) + (size_t)(h * 128 + j * 64) * (size_t)K + T2 * 64;
        ushort_t* l = lds + ((op * 2 + dd) * 2 + h) * 8192 + j * 4096 + wave * 512;
        gload16(g, l);
    };
    auto stageAB8 = [&](int dd, int T2) {
        stage1(0, dd, 0, 0, T2); stage1(0, dd, 0, 1, T2);
        stage1(0, dd, 1, 0, T2); stage1(0, dd, 1, 1, T2);
        stage1(1, dd, 0, 0, T2); stage1(1, dd, 0, 1, T2);
        stage1(1, dd, 1, 0, T2); stage1(1, dd, 1, 1, T2);
    };

    const int chunk0 = ((fk) ^ (fr & 7)) * 8;
    const int chunk1 = ((4 + fk) ^ (fr & 7)) * 8;

    auto loadA4 = [&](int dd, int kh, int qm, bf16x8* dst) {
        const ushort_t* base = lds + ((0 * 2 + dd) * 2 + wm) * 8192;
        const int ck = kh ? chunk1 : chunk0;
#pragma unroll
        for (int mi = 0; mi < 4; ++mi)
            dst[mi] = *(const bf16x8*)(base + (qm * 64 + mi * 16 + fr) * 64 + ck);
    };
    auto loadB4 = [&](int dd, int kh, bf16x8* dst) {
        const ushort_t* base = lds + ((1 * 2 + dd) * 2 + (wn >> 1)) * 8192;
        const int ck = kh ? chunk1 : chunk0;
#pragma unroll
        for (int ni = 0; ni < 4; ++ni)
            dst[ni] = *(const bf16x8*)(base + ((wn & 1) * 64 + ni * 16 + fr) * 64 + ck);
    };

    f32x4 acc[8][4];
#pragma unroll
    for (int i = 0; i < 8; ++i)
#pragma unroll
        for (int j = 0; j < 4; ++j) acc[i][j] = f32x4{0.f, 0.f, 0.f, 0.f};

    stageAB8(0, 0);
    asm volatile("s_waitcnt vmcnt(0)" ::: "memory");
    BARRIER();

    for (int T = 0; T < NT; ++T) {
        const int d = T & 1;
        bf16x8 a0[4], a1[4], a2[4], a3[4], b0[4], b1[4];
        loadB4(d, 0, b0);
        loadA4(d, 0, 0, a0);
        if (T + 1 < NT) stageAB8(d ^ 1, T + 1);
        loadA4(d, 0, 1, a1);
        MMX(acc, 0, a0, b0);
        loadB4(d, 1, b1);
        loadA4(d, 1, 0, a2);
        MMX(acc, 1, a1, b0);
        loadA4(d, 1, 1, a3);
        MMX(acc, 0, a2, b1);
        MMX(acc, 1, a3, b1);
        TILE_SYNC();
    }

    if (EPI == 0) {
#pragma unroll
        for (int mi8 = 0; mi8 < 8; ++mi8) {
            const int row0 = mb * 256 + wm * 128 + (mi8 >> 2) * 64 + (mi8 & 3) * 16 + fk * 4;
#pragma unroll
            for (int ni = 0; ni < 4; ++ni) {
                const int col = nb * 256 + wn * 64 + ni * 16 + fr;
                const float bias = epi_vec[col];
                f32x4 v = acc[mi8][ni];
#pragma unroll
                for (int j = 0; j < 4; ++j)
                    C[(size_t)(row0 + j) * N + col] = f2bf(fmaxf(v[j] + bias, 0.f));
            }
        }
    } else if (EPI == 1) {
        float rsum[8][4];
        float csum[4] = {0.f, 0.f, 0.f, 0.f};
#pragma unroll
        for (int mi8 = 0; mi8 < 8; ++mi8) {
            const int row0 = mb * 256 + wm * 128 + (mi8 >> 2) * 64 + (mi8 & 3) * 16 + fk * 4;
#pragma unroll
            for (int j = 0; j < 4; ++j) rsum[mi8][j] = 0.f;
#pragma unroll
            for (int ni = 0; ni < 4; ++ni) {
                const int col = nb * 256 + wn * 64 + ni * 16 + fr;
                f32x4 v = acc[mi8][ni];
#pragma unroll
                for (int j = 0; j < 4; ++j) {
                    float x = __expf(v[j]);
                    C[(size_t)(row0 + j) * N + col] = f2bf(x);
                    rsum[mi8][j] += x;
                    csum[ni] += x;
                }
            }
        }
#pragma unroll
        for (int mi8 = 0; mi8 < 8; ++mi8)
#pragma unroll
            for (int j = 0; j < 4; ++j) {
                float s = rsum[mi8][j];
                s += __shfl_xor(s, 1); s += __shfl_xor(s, 2);
                s += __shfl_xor(s, 4); s += __shfl_xor(s, 8);
                rsum[mi8][j] = s;
            }
        if (fr == 0) {
#pragma unroll
            for (int mi8 = 0; mi8 < 8; ++mi8)
#pragma unroll
                for (int j = 0; j < 4; ++j)
                    rowredp[wn * 256 + wm * 128 + (mi8 >> 2) * 64 + (mi8 & 3) * 16 + fk * 4 + j] = rsum[mi8][j];
        }
#pragma unroll
        for (int ni = 0; ni < 4; ++ni) {
            float s = csum[ni];
            s += __shfl_down(s, 32);
            s += __shfl_down(s, 16);
            csum[ni] = s;
        }
        if (fk == 0) {
#pragma unroll
            for (int ni = 0; ni < 4; ++ni) redp[wm * 256 + wn * 64 + ni * 16 + fr] = csum[ni];
        }
        BARRIER();
        if (t < 256) {
            rowp[(size_t)nb * M + mb * 256 + t] =
                rowredp[t] + rowredp[256 + t] + rowredp[512 + t] + rowredp[768 + t];
            colp[(size_t)mb * N + nb * 256 + t] = redp[t] + redp[256 + t];
        }
    } else {   // EPI == 3
        float cs[4] = {0.f, 0.f, 0.f, 0.f};
#pragma unroll
        for (int ni = 0; ni < 4; ++ni) {
            const int col = nb * 256 + wn * 64 + ni * 16 + fr;
            const float bias = epi_vec[col];
#pragma unroll
            for (int mi8 = 0; mi8 < 8; ++mi8) {
                f32x4 v = acc[mi8][ni];
#pragma unroll
                for (int j = 0; j < 4; ++j) cs[ni] += fmaxf(v[j] + bias, 0.f);
            }
        }
#pragma unroll
        for (int ni = 0; ni < 4; ++ni) {
            float s = cs[ni];
            s += __shfl_down(s, 32);
            s += __shfl_down(s, 16);
            cs[ni] = s;
        }
        if (fk == 0) {
#pragma unroll
            for (int ni = 0; ni < 4; ++ni) redp[wm * 256 + wn * 64 + ni * 16 + fr] = cs[ni];
        }
        BARRIER();
        if (t < 256) {
            float* colpart = (float*)C;
            colpart[(size_t)mb * N + nb * 256 + t] = redp[t] + redp[256 + t];
        }
    }
    asm volatile("s_waitcnt vmcnt(0)" ::: "memory");
}

// ---------------------------------------------------------------------------
// OCCUPANCY PROBE: BK=32 double-buffered, 64 KB LDS, __launch_bounds__(512,4)
// (explicitly request 2 blocks/CU). r14-verified math; used ONLY for the
// four 512-grid g-MLP dispatches. EPI: 0 bias+relu, 3 relu+colsum.
// ---------------------------------------------------------------------------
template<int EPI>
__global__ __launch_bounds__(512, 4) void gemm256_o2(
        const ushort_t* __restrict__ A, const ushort_t* __restrict__ Bt,
        ushort_t* __restrict__ C, int M, int N, int K,
        const float* __restrict__ epi_vec)
{
    __shared__ __align__(16) ushort_t lds[32768];   // 64KB total
    float* redp = (float*)lds;                       // epilogue alias

    const int nN = N >> 8;
    const int nwg = (int)gridDim.x;
    const int orig = (int)blockIdx.x;
    const int q = nwg >> 3, r = nwg & 7, xcd = orig & 7;
    const int wgid = (xcd < r ? xcd * (q + 1) : r * (q + 1) + (xcd - r) * q) + (orig >> 3);
    const int mb = wgid / nN, nb = wgid % nN;

    const int t = (int)threadIdx.x;
    const int lane = t & 63;
    const int wave = t >> 6;
    const int wm = wave >> 2;
    const int wn = wave & 3;
    const int fr = lane & 15;
    const int fk = lane >> 4;

    const int NT = K >> 5;            // BK = 32

    const int l8 = lane >> 3;
    const int cc = (lane & 7) ^ l8;
    const int growL = wave * 8 + l8 + ((cc >> 2) << 7);
    const int gcolL = (cc & 3) * 8;
    const ushort_t* gA = A + (size_t)(mb * 256 + growL) * (size_t)K + gcolL;
    const ushort_t* gB = Bt + (size_t)(nb * 256 + growL) * (size_t)K + gcolL;

    auto stage1 = [&](int op, int dd, int j, int T2) {
        const ushort_t* g = (op ? gB : gA) + (size_t)(j * 64) * (size_t)K + T2 * 32;
        ushort_t* l = lds + (op * 2 + dd) * 8192 + j * 4096 + wave * 512;
        gload16(g, l);
    };
    auto stage4 = [&](int dd, int T2) {
        stage1(0, dd, 0, T2); stage1(0, dd, 1, T2);
        stage1(1, dd, 0, T2); stage1(1, dd, 1, T2);
    };

    const int chunkA = ((fk + 4 * wm) ^ (fr & 7)) * 8;
    const int chunkB = ((fk + 4 * (wn >> 1)) ^ (fr & 7)) * 8;

    auto loadA4 = [&](int dd, int half, bf16x8* dst) {
        const ushort_t* base = lds + (0 * 2 + dd) * 8192 + chunkA + (half * 64 + fr) * 64;
#pragma unroll
        for (int mi = 0; mi < 4; ++mi)
            dst[mi] = *(const bf16x8*)(base + mi * 16 * 64);
    };
    auto loadB4 = [&](int dd, bf16x8* dst) {
        const ushort_t* base = lds + (1 * 2 + dd) * 8192 + chunkB + ((wn & 1) * 64 + fr) * 64;
#pragma unroll
        for (int ni = 0; ni < 4; ++ni)
            dst[ni] = *(const bf16x8*)(base + ni * 16 * 64);
    };

    f32x4 acc[8][4];
#pragma unroll
    for (int i = 0; i < 8; ++i)
#pragma unroll
        for (int j = 0; j < 4; ++j) acc[i][j] = f32x4{0.f, 0.f, 0.f, 0.f};

    stage4(0, 0);
    asm volatile("s_waitcnt vmcnt(0)" ::: "memory");
    BARRIER();

    for (int T = 0; T < NT; ++T) {
        const int d = T & 1;
        bf16x8 al[4], ah[4], bv[4];
        loadB4(d, bv);
        loadA4(d, 0, al);
        if (T + 1 < NT) stage4(d ^ 1, T + 1);
        loadA4(d, 1, ah);
        MMX(acc, 0, al, bv);   // rows 0-63 of wave tile
        MMX(acc, 1, ah, bv);   // rows 64-127
        TILE_SYNC();
    }

    if (EPI == 0) {
#pragma unroll
        for (int mi8 = 0; mi8 < 8; ++mi8) {
            const int row0 = mb * 256 + wm * 128 + mi8 * 16 + fk * 4;
#pragma unroll
            for (int ni = 0; ni < 4; ++ni) {
                const int col = nb * 256 + wn * 64 + ni * 16 + fr;
                const float bias = epi_vec[col];
                f32x4 v = acc[mi8][ni];
#pragma unroll
                for (int j = 0; j < 4; ++j)
                    C[(size_t)(row0 + j) * N + col] = f2bf(fmaxf(v[j] + bias, 0.f));
            }
        }
    } else {   // EPI == 3
        float cs[4] = {0.f, 0.f, 0.f, 0.f};
#pragma unroll
        for (int ni = 0; ni < 4; ++ni) {
            const int col = nb * 256 + wn * 64 + ni * 16 + fr;
            const float bias = epi_vec[col];
#pragma unroll
            for (int mi8 = 0; mi8 < 8; ++mi8) {
                f32x4 v = acc[mi8][ni];
#pragma unroll
                for (int j = 0; j < 4; ++j) cs[ni] += fmaxf(v[j] + bias, 0.f);
            }
        }
#pragma unroll
        for (int ni = 0; ni < 4; ++ni) {
            float s = cs[ni];
            s += __shfl_down(s, 32);
            s += __shfl_down(s, 16);
            cs[ni] = s;
        }
        if (fk == 0) {
#pragma unroll
            for (int ni = 0; ni < 4; ++ni) redp[wm * 256 + wn * 64 + ni * 16 + fr] = cs[ni];
        }
        BARRIER();
        if (t < 256) {
            float* colpart = (float*)C;
            colpart[(size_t)mb * N + nb * 256 + t] = redp[t] + redp[256 + t];
        }
    }
    asm volatile("s_waitcnt vmcnt(0)" ::: "memory");
}

// ---------------------------------------------------------------------------
// 128x128 m97-style GEMM, kept for EPI=2 (beta/alpha; small grids).
// ---------------------------------------------------------------------------
template<int EPI>
__global__ __launch_bounds__(256) void gemm_bt(
        const ushort_t* __restrict__ A, const ushort_t* __restrict__ Bt,
        ushort_t* __restrict__ C, int M, int N, int K,
        const float* __restrict__ epi_vec)
{
    __shared__ __align__(16) ushort_t As[128 * 32];
    __shared__ __align__(16) ushort_t Bs[128 * 32];

    const int nN = N >> 7;
    const int nwg = (int)gridDim.x;
    const int orig = (int)blockIdx.x;
    const int q = nwg >> 3, r = nwg & 7, xcd = orig & 7;
    const int wgid = (xcd < r ? xcd * (q + 1) : r * (q + 1) + (xcd - r) * q) + (orig >> 3);
    const int mb = wgid / nN, nb = wgid % nN;

    const int t = (int)threadIdx.x;
    const int lane = t & 63;
    const int wave = t >> 6;
    const int wrow = (wave >> 1) << 6;
    const int wcol = (wave & 1) << 6;
    const int fr = lane & 15;
    const int fk = lane >> 4;

    int aoffe[4], boffe[4];
#pragma unroll
    for (int i = 0; i < 4; ++i) {
        int ra = wrow + i * 16 + fr;
        aoffe[i] = ra * 32 + (((fk ^ (ra >> 1)) & 3) << 3);
        int rb = wcol + i * 16 + fr;
        boffe[i] = rb * 32 + (((fk ^ (rb >> 1)) & 3) << 3);
    }

    const int srow = t >> 2;
    const int sslot = (t & 3) ^ ((srow >> 1) & 3);
    const ushort_t* ga = A + (size_t)(mb * 128 + srow) * K + sslot * 8;
    const ushort_t* gb = Bt + (size_t)(nb * 128 + srow) * K + sslot * 8;
    const size_t rowskip = (size_t)64 * K;
    ushort_t* lA0 = As + wave * 512;
    ushort_t* lA1 = As + 2048 + wave * 512;
    ushort_t* lB0 = Bs + wave * 512;
    ushort_t* lB1 = Bs + 2048 + wave * 512;

    f32x4 acc[4][4] = {};

    const int kiters = K >> 5;
    for (int kt = 0; kt < kiters; ++kt) {
        gload16(ga, lA0);
        gload16(ga + rowskip, lA1);
        gload16(gb, lB0);
        gload16(gb + rowskip, lB1);
        __syncthreads();
        bf16x8 af[4], bvv[4];
#pragma unroll
        for (int i = 0; i < 4; ++i) af[i] = *(const bf16x8*)(As + aoffe[i]);
#pragma unroll
        for (int i = 0; i < 4; ++i) bvv[i] = *(const bf16x8*)(Bs + boffe[i]);
#pragma unroll
        for (int mi = 0; mi < 4; ++mi)
#pragma unroll
            for (int ni = 0; ni < 4; ++ni)
                acc[mi][ni] = __builtin_amdgcn_mfma_f32_16x16x32_bf16(af[mi], bvv[ni], acc[mi][ni], 0, 0, 0);
        __syncthreads();
        ga += 32; gb += 32;
    }

#pragma unroll
    for (int mi = 0; mi < 4; ++mi) {
        const int row0 = mb * 128 + wrow + mi * 16 + fk * 4;
#pragma unroll
        for (int ni = 0; ni < 4; ++ni) {
            const int col = nb * 128 + wcol + ni * 16 + fr;
            float bias = (EPI == 0) ? epi_vec[col] : 0.f;
            f32x4 v = acc[mi][ni];
#pragma unroll
            for (int j = 0; j < 4; ++j) {
                int row = row0 + j;
                float x = v[j];
                if (EPI == 0)      x = fmaxf(x + bias, 0.f);
                else if (EPI == 1) x = __expf(x);
                else               x = x * epi_vec[row];
                C[(size_t)row * N + col] = f2bf(x);
            }
        }
    }
}

// fp32 -> bf16 flat convert (4 floats/thread)
__global__ __launch_bounds__(256) void convert_x_k(const float* __restrict__ in,
                                                   ushort_t* __restrict__ out)
{
    size_t i = ((size_t)blockIdx.x * 256 + threadIdx.x) * 4;
    float4 v = *(const float4*)(in + i);
    us4 o;
    o[0] = f2bf(v.x); o[1] = f2bf(v.y); o[2] = f2bf(v.z); o[3] = f2bf(v.w);
    *(us4*)(out + i) = o;
}

// bf16 batched transpose: in (Z,R,C) -> out (Z,C,R)
__global__ void transpose_bf16_k(const ushort_t* __restrict__ in, ushort_t* __restrict__ out,
                                 int R, int C)
{
    __shared__ ushort_t tile[32][33];
    size_t bo = (size_t)blockIdx.z * R * C;
    const ushort_t* pin = in + bo;
    ushort_t* pout = out + bo;
    int c0 = blockIdx.x << 5, r0 = blockIdx.y << 5;
    int tx = threadIdx.x, ty = threadIdx.y;    // (32,8)
#pragma unroll
    for (int i = 0; i < 4; ++i)
        tile[ty + i * 8][tx] = pin[(size_t)(r0 + ty + i * 8) * C + c0 + tx];
    __syncthreads();
#pragma unroll
    for (int i = 0; i < 4; ++i)
        pout[(size_t)(c0 + ty + i * 8) * R + r0 + tx] = tile[tx][ty + i * 8];
}

// in-place transpose of a 4096x4096 bf16 matrix via 32x32 tile-pair swap
__global__ void transpose_inplace_k(ushort_t* __restrict__ Mx)
{
    int bi = blockIdx.y, bj = blockIdx.x;      // 128x128 tiles
    if (bi > bj) return;
    __shared__ ushort_t ta[32][33], tb[32][33];
    int r0 = bi << 5, c0 = bj << 5;
    int tx = threadIdx.x, ty = threadIdx.y;    // (32,8)
#pragma unroll
    for (int i = 0; i < 4; ++i)
        ta[ty + i * 8][tx] = Mx[(size_t)(r0 + ty + i * 8) * 4096 + c0 + tx];
    if (bi < bj) {
#pragma unroll
        for (int i = 0; i < 4; ++i)
            tb[ty + i * 8][tx] = Mx[(size_t)(c0 + ty + i * 8) * 4096 + r0 + tx];
    }
    __syncthreads();
#pragma unroll
    for (int i = 0; i < 4; ++i)
        Mx[(size_t)(c0 + ty + i * 8) * 4096 + r0 + tx] = ta[tx][ty + i * 8];
    if (bi < bj) {
#pragma unroll
        for (int i = 0; i < 4; ++i)
            Mx[(size_t)(r0 + ty + i * 8) * 4096 + c0 + tx] = tb[tx][ty + i * 8];
    }
}

// weight convert+transpose: in fp32 (R,C) -> out bf16 (C,R)
__global__ void wt_transpose_k(const float* __restrict__ in, ushort_t* __restrict__ out,
                               int R, int C)
{
    __shared__ ushort_t tile[32][33];
    int c0 = blockIdx.x << 5, r0 = blockIdx.y << 5;
    int tx = threadIdx.x, ty = threadIdx.y;    // (32,8)
#pragma unroll
    for (int i = 0; i < 4; ++i)
        tile[ty + i * 8][tx] = f2bf(in[(size_t)(r0 + ty + i * 8) * C + c0 + tx]);
    __syncthreads();
#pragma unroll
    for (int i = 0; i < 4; ++i)
        out[(size_t)(c0 + ty + i * 8) * R + r0 + tx] = tile[tx][ty + i * 8];
}

// recip of summed partials: out[idx] = 1 / sum_{i<16} p[i][idx]
__global__ __launch_bounds__(256) void rowrecip_k(const float* __restrict__ p,
                                                  float* __restrict__ out, int Mrows)
{
    int idx = blockIdx.x * 256 + threadIdx.x;
    float s = 0.f;
#pragma unroll
    for (int i = 0; i < 16; ++i) s += p[(size_t)i * Mrows + idx];
    out[idx] = 1.0f / s;
}

// reduce fused-colsum partials -> agg (2,4096)
__global__ __launch_bounds__(256) void agg_reduce_k(const float* __restrict__ part,
                                                    float* __restrict__ agg)
{
    int idx = blockIdx.x * 256 + threadIdx.x;  // 8192
    int g = idx >> 11, col = idx & 2047;
    int half = g >> 1, b = g & 1;
    const float* p = part + (size_t)half * 64 * 2048;
    float s = 0.f;
    for (int rr = 0; rr < 16; ++rr)
        s += p[(size_t)(b * 16 + rr) * 2048 + col] +
             p[(size_t)(32 + b * 16 + rr) * 2048 + col];
    agg[b * 4096 + half * 2048 + col] = s;
}

// h-MLP partial: part[kc][2][2048], kcs=16
__global__ __launch_bounds__(256) void h_part_k(const float* __restrict__ act,
                                                const float* __restrict__ W,
                                                float* __restrict__ part, int Kdim)
{
    int j = blockIdx.x * 256 + threadIdx.x;
    int kc = blockIdx.y;
    float a0 = 0.f, a1 = 0.f;
    int k0 = kc * 16;
#pragma unroll
    for (int i = 0; i < 16; ++i) {
        int k = k0 + i;
        float w = W[(size_t)k * 2048 + j];
        a0 += act[k] * w;
        a1 += act[Kdim + k] * w;
    }
    part[(size_t)(kc * 2 + 0) * 2048 + j] = a0;
    part[(size_t)(kc * 2 + 1) * 2048 + j] = a1;
}

__global__ __launch_bounds__(256) void h_reduce_mid_k(const float* __restrict__ part,
                                                      float* __restrict__ part2)
{
    int idx = blockIdx.x * 256 + threadIdx.x;
    int g2 = idx >> 12;
    int rrow = (idx >> 11) & 1, j = idx & 2047;
    float s = 0.f;
#pragma unroll
    for (int i = 0; i < 16; ++i)
        s += part[(size_t)(((g2 * 16 + i) * 2) + rrow) * 2048 + j];
    part2[(size_t)(g2 * 2 + rrow) * 2048 + j] = s;
}

__global__ __launch_bounds__(256) void h_reduce_k(const float* __restrict__ part2,
                                                  const float* __restrict__ bias,
                                                  float* __restrict__ out, int nkc)
{
    int idx = blockIdx.x * 256 + threadIdx.x;  // 2*2048
    int rrow = idx >> 11, j = idx & 2047;
    float s = 0.f;
    for (int kc = 0; kc < nkc; ++kc) s += part2[(size_t)(kc * 2 + rrow) * 2048 + j];
    s += bias[j];
    out[rrow * 2048 + j] = fmaxf(s, 0.f);
}

__global__ __launch_bounds__(256) void h3_k(const float* __restrict__ a2,
                                            const float* __restrict__ W,
                                            const float* __restrict__ b3,
                                            float* __restrict__ out)
{
    __shared__ float red[6][256];
    int t = threadIdx.x;
    float acc[6] = {0, 0, 0, 0, 0, 0};
    for (int k = t; k < 2048; k += 256) {
        float x0 = a2[k], x1 = a2[2048 + k];
#pragma unroll
        for (int c = 0; c < 3; ++c) {
            float w = W[k * 3 + c];
            acc[c] += x0 * w;
            acc[3 + c] += x1 * w;
        }
    }
#pragma unroll
    for (int c = 0; c < 6; ++c) red[c][t] = acc[c];
    __syncthreads();
    if (t < 6) {
        float s = 0.f;
        for (int i = 0; i < 256; ++i) s += red[t][i];
        s += b3[t < 3 ? t : t - 3];
        out[t] = fmaxf(s, 0.f);
    }
}

__global__ void diag_k(float* __restrict__ out, unsigned long long wsmb)
{
    if (threadIdx.x < 6) out[threadIdx.x] = 10000.0f + (float)wsmb;
}

// ---------------------------------------------------------------------------
// workspace layout (bytes) — ~214.7 MiB
// ---------------------------------------------------------------------------
constexpr size_t MB = 1024ull * 1024;
constexpr size_t OFF_W1T  = 0;
constexpr size_t OFF_W2T  = OFF_W1T  + 2048ull * 1024 * 2;
constexpr size_t OFF_W3T  = OFF_W2T  + 2048ull * 2048 * 2;
constexpr size_t OFF_XBF  = OFF_W3T  + 2048ull * 2048 * 2;       // 16384x1024 bf16
constexpr size_t OFF_R1   = OFF_XBF  + 16384ull * 1024 * 2;      // 64 MB
constexpr size_t OFF_R2   = OFF_R1   + 64 * MB;                  // 64 MB
constexpr size_t OFF_BETA = OFF_R2   + 64 * MB;
constexpr size_t OFF_ALPHA= OFF_BETA + 2ull * 4096 * 1024 * 2;
constexpr size_t OFF_PART = OFF_ALPHA+ 2ull * 4096 * 1024 * 2;   // 2x64x2048 fp32
constexpr size_t OFF_RS   = OFF_PART + 2ull * 128 * 2048 * 4;
constexpr size_t OFF_CS   = OFF_RS   + 4096 * 4;
constexpr size_t OFF_AGG  = OFF_CS   + 4096 * 4;
constexpr size_t OFF_ROWP = OFF_AGG  + 8192 * 4;                 // 16x4096 fp32
constexpr size_t OFF_COLP = OFF_ROWP + 16ull * 4096 * 4;         // 16x4096 fp32
constexpr size_t OFF_END  = OFF_COLP + 16ull * 4096 * 4;

extern "C" void kernel_launch(void* const* d_in, const int* in_sizes, int n_in,
                              void* d_out, int out_size, void* d_ws, size_t ws_size,
                              hipStream_t stream)
{
    const float* x1  = (const float*)d_in[0];
    const float* x2  = (const float*)d_in[1];
    const float* fW1 = (const float*)d_in[2];  const float* fb1 = (const float*)d_in[3];
    const float* fW2 = (const float*)d_in[4];  const float* fb2 = (const float*)d_in[5];
    const float* fW3 = (const float*)d_in[6];  const float* fb3 = (const float*)d_in[7];
    const float* gW1 = (const float*)d_in[8];  const float* gb1 = (const float*)d_in[9];
    const float* gW2 = (const float*)d_in[10]; const float* gb2 = (const float*)d_in[11];
    const float* gW3 = (const float*)d_in[12]; const float* gb3 = (const float*)d_in[13];
    const float* hW1 = (const float*)d_in[14]; const float* hb1 = (const float*)d_in[15];
    const float* hW2 = (const float*)d_in[16]; const float* hb2 = (const float*)d_in[17];
    const float* hW3 = (const float*)d_in[18]; const float* hb3 = (const float*)d_in[19];

    float* out = (float*)d_out;

    if (ws_size < OFF_END) {
        diag_k<<<1, 64, 0, stream>>>(out, (unsigned long long)(ws_size >> 20));
        return;
    }

    char* ws = (char*)d_ws;
    ushort_t* W1T  = (ushort_t*)(ws + OFF_W1T);
    ushort_t* W2T  = (ushort_t*)(ws + OFF_W2T);
    ushort_t* W3T  = (ushort_t*)(ws + OFF_W3T);
    ushort_t* XBF  = (ushort_t*)(ws + OFF_XBF);
    ushort_t* R1   = (ushort_t*)(ws + OFF_R1);
    ushort_t* R2   = (ushort_t*)(ws + OFF_R2);
    ushort_t* BETA = (ushort_t*)(ws + OFF_BETA);
    ushort_t* ALPHA= (ushort_t*)(ws + OFF_ALPHA);
    float* PART  = (float*)(ws + OFF_PART);
    float* RS    = (float*)(ws + OFF_RS);
    float* CS    = (float*)(ws + OFF_CS);
    float* AGG   = (float*)(ws + OFF_AGG);
    float* ROWP  = (float*)(ws + OFF_ROWP);
    float* COLP  = (float*)(ws + OFF_COLP);

    ushort_t* PING = R2;
    ushort_t* PONG = R2 + 16777216;                    // element offsets
    ushort_t* E    = R2;
    ushort_t* X1T  = R2 + 16777216;
    ushort_t* X2T  = R2 + 25165824;
    float* PARTH = (float*)(ws + OFF_R2);
    float* PART2 = (float*)(ws + OFF_R2 + 4 * MB);
    float* A1    = (float*)(ws + OFF_R2 + 6 * MB);
    float* A2    = (float*)(ws + OFF_R2 + 6 * MB + 16384);

    dim3 tb(32, 8);

    // 1) x -> bf16
    convert_x_k<<<8192, 256, 0, stream>>>(x1, XBF);
    convert_x_k<<<8192, 256, 0, stream>>>(x2, XBF + 8192ull * 1024);

    // 2) f-weights -> bf16 transposed
    wt_transpose_k<<<dim3(64, 32), tb, 0, stream>>>(fW1, W1T, 1024, 2048);
    wt_transpose_k<<<dim3(64, 64), tb, 0, stream>>>(fW2, W2T, 2048, 2048);
    wt_transpose_k<<<dim3(64, 64), tb, 0, stream>>>(fW3, W3T, 2048, 2048);

    // 3) f-MLP in 2 chunks of 8192 rows: XBF -> PING -> PONG -> F(R1)
    for (int c = 0; c < 2; ++c) {
        const ushort_t* src = XBF + (size_t)c * 8192 * 1024;
        ushort_t* dst = R1 + (size_t)c * 8192 * 2048;
        gemm256<0><<<256, 512, 0, stream>>>(src, W1T, PING, 8192, 2048, 1024, fb1, nullptr, nullptr);
        gemm256<0><<<256, 512, 0, stream>>>(PING, W2T, PONG, 8192, 2048, 2048, fb2, nullptr, nullptr);
        gemm256<0><<<256, 512, 0, stream>>>(PONG, W3T, dst, 8192, 2048, 2048, fb3, nullptr, nullptr);
    }

    // 4) x1^T -> X1T, x2^T -> X2T
    transpose_bf16_k<<<dim3(32, 128, 2), tb, 0, stream>>>(XBF, X1T, 4096, 1024);
    transpose_bf16_k<<<dim3(32, 128, 2), tb, 0, stream>>>(XBF + 8192ull * 1024, X2T, 4096, 1024);

    // 5) attention per batch: ONE score GEMM (E + rowsum + colsum partials),
    //    beta from E, in-place transpose E -> E^T, alpha from E^T.
    for (int b = 0; b < 2; ++b) {
        const ushort_t* fa  = R1 + (size_t)b * 4096 * 2048;
        const ushort_t* fbp = R1 + (size_t)(8192 + b * 4096) * 2048;
        gemm256<1><<<256, 512, 0, stream>>>(fa, fbp, E, 4096, 4096, 2048, nullptr, ROWP, COLP);
        rowrecip_k<<<16, 256, 0, stream>>>(ROWP, RS, 4096);
        rowrecip_k<<<16, 256, 0, stream>>>(COLP, CS, 4096);
        gemm_bt<2><<<256, 256, 0, stream>>>(E, X2T + (size_t)b * 1024 * 4096,
                                            BETA + (size_t)b * 4096 * 1024,
                                            4096, 1024, 4096, RS);
        transpose_inplace_k<<<dim3(128, 128), tb, 0, stream>>>(E);
        gemm_bt<2><<<256, 256, 0, stream>>>(E, X1T + (size_t)b * 1024 * 4096,
                                            ALPHA + (size_t)b * 4096 * 1024,
                                            4096, 1024, 4096, CS);
    }

    // 6) g-weights overwrite the W region
    wt_transpose_k<<<dim3(64, 32), tb, 0, stream>>>(gW1, W1T, 1024, 2048);
    wt_transpose_k<<<dim3(64, 64), tb, 0, stream>>>(gW2, W2T, 2048, 2048);
    wt_transpose_k<<<dim3(64, 64), tb, 0, stream>>>(gW3, W3T, 2048, 2048);

    // 7) g-MLP, 2 chunks of 16384 rows; 512-grid L2/L3 use the 2-block probe
    //    kernel (gemm256_o2); L3 fuses column sums (EPI=3)
    for (int c = 0; c < 2; ++c) {
        const ushort_t* xsrc = XBF + (size_t)c * 8192 * 1024;
        const ushort_t* asrc = (c == 0) ? BETA : ALPHA;
        gemm256<0><<<256, 512, 0, stream>>>(xsrc, W1T, R1, 8192, 2048, 1024, gb1, nullptr, nullptr);
        gemm256<0><<<256, 512, 0, stream>>>(asrc, W1T, R1 + 8192ull * 2048, 8192, 2048, 1024, gb1, nullptr, nullptr);
        gemm256_o2<0><<<512, 512, 0, stream>>>(R1, W2T, R2, 16384, 2048, 2048, gb2);
        gemm256_o2<3><<<512, 512, 0, stream>>>(R2, W3T,
                                               (ushort_t*)(PART + (size_t)c * 64 * 2048),
                                               16384, 2048, 2048, gb3);
    }
    agg_reduce_k<<<32, 256, 0, stream>>>(PART, AGG);

    // 8) h-MLP (fp32, deterministic tree reduction; scratch in dead R2)
    h_part_k<<<dim3(8, 256), 256, 0, stream>>>(AGG, hW1, PARTH, 4096);
    h_reduce_mid_k<<<256, 256, 0, stream>>>(PARTH, PART2);
    h_reduce_k<<<16, 256, 0, stream>>>(PART2, hb1, A1, 16);
    h_part_k<<<dim3(8, 128), 256, 0, stream>>>(A1, hW2, PARTH, 2048);
    h_reduce_mid_k<<<128, 256, 0, stream>>>(PARTH, PART2);
    h_reduce_k<<<16, 256, 0, stream>>>(PART2, hb2, A2, 8);
    h3_k<<<1, 256, 0, stream>>>(A2, hW3, hb3, out);
}

// Round 17
// 1481.728 us; speedup vs baseline: 4.0527x; 4.0527x over previous
//
#include <hip/hip_runtime.h>
#include <hip/hip_bf16.h>
#include <cstdint>
#include <cstddef>

typedef unsigned short ushort_t;
typedef __attribute__((ext_vector_type(8))) __bf16 bf16x8;
typedef __attribute__((ext_vector_type(4))) float f32x4;
typedef __attribute__((ext_vector_type(4))) unsigned short us4;

__device__ __forceinline__ unsigned short f2bf(float f) {
    union { __hip_bfloat16 h; unsigned short u; } v;
    v.h = __float2bfloat16(f);
    return v.u;
}
__device__ __forceinline__ float bf2f(unsigned short u) {
    union { unsigned int i; float f; } v;
    v.i = ((unsigned int)u) << 16;
    return v.f;
}

__device__ __forceinline__ void gload16(const void* g, void* l) {
    __builtin_amdgcn_global_load_lds((const __attribute__((address_space(1))) void*)g,
                                     (__attribute__((address_space(3))) void*)l,
                                     16, 0, 0);
}

#define BARRIER() asm volatile("s_barrier" ::: "memory")

#define MMX(ACC, QM, AV, BV) do {                                                \
    _Pragma("unroll") for (int mi = 0; mi < 4; ++mi)                             \
    _Pragma("unroll") for (int ni = 0; ni < 4; ++ni)                             \
        ACC[(QM) * 4 + mi][ni] = __builtin_amdgcn_mfma_f32_16x16x32_bf16(        \
            AV[mi], BV[ni], ACC[(QM) * 4 + mi][ni], 0, 0, 0);                    \
} while (0)

#define TILE_SYNC() do {                                                         \
    __builtin_amdgcn_sched_barrier(0);                                           \
    asm volatile("s_waitcnt lgkmcnt(0) vmcnt(0)" ::: "memory");                  \
    __builtin_amdgcn_sched_barrier(0);                                           \
    BARRIER();                                                                   \
} while (0)

// ---------------------------------------------------------------------------
// 256x256 GEMM, BK=64, register-pipelined (session best, r15): C = A @ Bt^T.
// 512 threads = 8 waves (2M x 4N), per-wave 128x64 output. Static LDS 128 KB
// (epilogue reduce aliased into tile LDS). ONE fortified sync per tile.
// NOTE: occupancy is REGISTER-bound at 2 waves/SIMD (acc[8][4]=128 regs +
// ~100 arch VGPRs vs unified 512/wave file) -> exactly 1 block/CU; r16 probe
// proved forcing 2 blocks spills (VGPR 64, 2.2GB scratch fetch, 10x slower).
// EPI: 0 bias+relu, 1 exp (+rowsum AND colsum partials), 3 relu+colsum.
// Requires M%256==0, N%256==0, K%64==0, K>=128, grid%8==0.
// ---------------------------------------------------------------------------
template<int EPI>
__global__ __launch_bounds__(512) void gemm256(
        const ushort_t* __restrict__ A, const ushort_t* __restrict__ Bt,
        ushort_t* __restrict__ C, int M, int N, int K,
        const float* __restrict__ epi_vec, float* __restrict__ rowp,
        float* __restrict__ colp)
{
    __shared__ __align__(16) ushort_t lds[65536];   // 128KB
    float* redp    = (float*)lds;
    float* rowredp = (float*)(lds + 1024);

    const int nN = N >> 8;
    const int nwg = (int)gridDim.x;
    const int orig = (int)blockIdx.x;
    const int q = nwg >> 3, r = nwg & 7, xcd = orig & 7;
    const int wgid = (xcd < r ? xcd * (q + 1) : r * (q + 1) + (xcd - r) * q) + (orig >> 3);
    const int mb = wgid / nN, nb = wgid % nN;

    const int t = (int)threadIdx.x;
    const int lane = t & 63;
    const int wave = t >> 6;
    const int wm = wave >> 2;
    const int wn = wave & 3;
    const int fr = lane & 15;
    const int fk = lane >> 4;

    const int NT = K >> 6;

    const int l8 = lane >> 3;
    const int lcc = ((lane & 7) ^ (l8 & 7)) * 8;
    const ushort_t* gA = A + (size_t)(mb * 256 + wave * 8 + l8) * (size_t)K + lcc;
    const ushort_t* gB = Bt + (size_t)(nb * 256 + wave * 8 + l8) * (size_t)K + lcc;

    auto stage1 = [&](int op, int dd, int h, int j, int T2) {
        const ushort_t* g = (op ? gB : gA) + (size_t)(h * 128 + j * 64) * (size_t)K + T2 * 64;
        ushort_t* l = lds + ((op * 2 + dd) * 2 + h) * 8192 + j * 4096 + wave * 512;
        gload16(g, l);
    };
    auto stageAB8 = [&](int dd, int T2) {
        stage1(0, dd, 0, 0, T2); stage1(0, dd, 0, 1, T2);
        stage1(0, dd, 1, 0, T2); stage1(0, dd, 1, 1, T2);
        stage1(1, dd, 0, 0, T2); stage1(1, dd, 0, 1, T2);
        stage1(1, dd, 1, 0, T2); stage1(1, dd, 1, 1, T2);
    };

    const int chunk0 = ((fk) ^ (fr & 7)) * 8;
    const int chunk1 = ((4 + fk) ^ (fr & 7)) * 8;

    auto loadA4 = [&](int dd, int kh, int qm, bf16x8* dst) {
        const ushort_t* base = lds + ((0 * 2 + dd) * 2 + wm) * 8192;
        const int ck = kh ? chunk1 : chunk0;
#pragma unroll
        for (int mi = 0; mi < 4; ++mi)
            dst[mi] = *(const bf16x8*)(base + (qm * 64 + mi * 16 + fr) * 64 + ck);
    };
    auto loadB4 = [&](int dd, int kh, bf16x8* dst) {
        const ushort_t* base = lds + ((1 * 2 + dd) * 2 + (wn >> 1)) * 8192;
        const int ck = kh ? chunk1 : chunk0;
#pragma unroll
        for (int ni = 0; ni < 4; ++ni)
            dst[ni] = *(const bf16x8*)(base + ((wn & 1) * 64 + ni * 16 + fr) * 64 + ck);
    };

    f32x4 acc[8][4];
#pragma unroll
    for (int i = 0; i < 8; ++i)
#pragma unroll
        for (int j = 0; j < 4; ++j) acc[i][j] = f32x4{0.f, 0.f, 0.f, 0.f};

    stageAB8(0, 0);
    asm volatile("s_waitcnt vmcnt(0)" ::: "memory");
    BARRIER();

    for (int T = 0; T < NT; ++T) {
        const int d = T & 1;
        bf16x8 a0[4], a1[4], a2[4], a3[4], b0[4], b1[4];
        loadB4(d, 0, b0);
        loadA4(d, 0, 0, a0);
        if (T + 1 < NT) stageAB8(d ^ 1, T + 1);
        loadA4(d, 0, 1, a1);
        MMX(acc, 0, a0, b0);
        loadB4(d, 1, b1);
        loadA4(d, 1, 0, a2);
        MMX(acc, 1, a1, b0);
        loadA4(d, 1, 1, a3);
        MMX(acc, 0, a2, b1);
        MMX(acc, 1, a3, b1);
        TILE_SYNC();
    }

    if (EPI == 0) {
#pragma unroll
        for (int mi8 = 0; mi8 < 8; ++mi8) {
            const int row0 = mb * 256 + wm * 128 + (mi8 >> 2) * 64 + (mi8 & 3) * 16 + fk * 4;
#pragma unroll
            for (int ni = 0; ni < 4; ++ni) {
                const int col = nb * 256 + wn * 64 + ni * 16 + fr;
                const float bias = epi_vec[col];
                f32x4 v = acc[mi8][ni];
#pragma unroll
                for (int j = 0; j < 4; ++j)
                    C[(size_t)(row0 + j) * N + col] = f2bf(fmaxf(v[j] + bias, 0.f));
            }
        }
    } else if (EPI == 1) {
        float rsum[8][4];
        float csum[4] = {0.f, 0.f, 0.f, 0.f};
#pragma unroll
        for (int mi8 = 0; mi8 < 8; ++mi8) {
            const int row0 = mb * 256 + wm * 128 + (mi8 >> 2) * 64 + (mi8 & 3) * 16 + fk * 4;
#pragma unroll
            for (int j = 0; j < 4; ++j) rsum[mi8][j] = 0.f;
#pragma unroll
            for (int ni = 0; ni < 4; ++ni) {
                const int col = nb * 256 + wn * 64 + ni * 16 + fr;
                f32x4 v = acc[mi8][ni];
#pragma unroll
                for (int j = 0; j < 4; ++j) {
                    float x = __expf(v[j]);
                    C[(size_t)(row0 + j) * N + col] = f2bf(x);
                    rsum[mi8][j] += x;
                    csum[ni] += x;
                }
            }
        }
#pragma unroll
        for (int mi8 = 0; mi8 < 8; ++mi8)
#pragma unroll
            for (int j = 0; j < 4; ++j) {
                float s = rsum[mi8][j];
                s += __shfl_xor(s, 1); s += __shfl_xor(s, 2);
                s += __shfl_xor(s, 4); s += __shfl_xor(s, 8);
                rsum[mi8][j] = s;
            }
        if (fr == 0) {
#pragma unroll
            for (int mi8 = 0; mi8 < 8; ++mi8)
#pragma unroll
                for (int j = 0; j < 4; ++j)
                    rowredp[wn * 256 + wm * 128 + (mi8 >> 2) * 64 + (mi8 & 3) * 16 + fk * 4 + j] = rsum[mi8][j];
        }
#pragma unroll
        for (int ni = 0; ni < 4; ++ni) {
            float s = csum[ni];
            s += __shfl_down(s, 32);
            s += __shfl_down(s, 16);
            csum[ni] = s;
        }
        if (fk == 0) {
#pragma unroll
            for (int ni = 0; ni < 4; ++ni) redp[wm * 256 + wn * 64 + ni * 16 + fr] = csum[ni];
        }
        BARRIER();
        if (t < 256) {
            rowp[(size_t)nb * M + mb * 256 + t] =
                rowredp[t] + rowredp[256 + t] + rowredp[512 + t] + rowredp[768 + t];
            colp[(size_t)mb * N + nb * 256 + t] = redp[t] + redp[256 + t];
        }
    } else {   // EPI == 3
        float cs[4] = {0.f, 0.f, 0.f, 0.f};
#pragma unroll
        for (int ni = 0; ni < 4; ++ni) {
            const int col = nb * 256 + wn * 64 + ni * 16 + fr;
            const float bias = epi_vec[col];
#pragma unroll
            for (int mi8 = 0; mi8 < 8; ++mi8) {
                f32x4 v = acc[mi8][ni];
#pragma unroll
                for (int j = 0; j < 4; ++j) cs[ni] += fmaxf(v[j] + bias, 0.f);
            }
        }
#pragma unroll
        for (int ni = 0; ni < 4; ++ni) {
            float s = cs[ni];
            s += __shfl_down(s, 32);
            s += __shfl_down(s, 16);
            cs[ni] = s;
        }
        if (fk == 0) {
#pragma unroll
            for (int ni = 0; ni < 4; ++ni) redp[wm * 256 + wn * 64 + ni * 16 + fr] = cs[ni];
        }
        BARRIER();
        if (t < 256) {
            float* colpart = (float*)C;
            colpart[(size_t)mb * N + nb * 256 + t] = redp[t] + redp[256 + t];
        }
    }
    asm volatile("s_waitcnt vmcnt(0)" ::: "memory");
}

// ---------------------------------------------------------------------------
// 128x128 m97-style GEMM, kept for EPI=2 (beta/alpha; small grids).
// ---------------------------------------------------------------------------
template<int EPI>
__global__ __launch_bounds__(256) void gemm_bt(
        const ushort_t* __restrict__ A, const ushort_t* __restrict__ Bt,
        ushort_t* __restrict__ C, int M, int N, int K,
        const float* __restrict__ epi_vec)
{
    __shared__ __align__(16) ushort_t As[128 * 32];
    __shared__ __align__(16) ushort_t Bs[128 * 32];

    const int nN = N >> 7;
    const int nwg = (int)gridDim.x;
    const int orig = (int)blockIdx.x;
    const int q = nwg >> 3, r = nwg & 7, xcd = orig & 7;
    const int wgid = (xcd < r ? xcd * (q + 1) : r * (q + 1) + (xcd - r) * q) + (orig >> 3);
    const int mb = wgid / nN, nb = wgid % nN;

    const int t = (int)threadIdx.x;
    const int lane = t & 63;
    const int wave = t >> 6;
    const int wrow = (wave >> 1) << 6;
    const int wcol = (wave & 1) << 6;
    const int fr = lane & 15;
    const int fk = lane >> 4;

    int aoffe[4], boffe[4];
#pragma unroll
    for (int i = 0; i < 4; ++i) {
        int ra = wrow + i * 16 + fr;
        aoffe[i] = ra * 32 + (((fk ^ (ra >> 1)) & 3) << 3);
        int rb = wcol + i * 16 + fr;
        boffe[i] = rb * 32 + (((fk ^ (rb >> 1)) & 3) << 3);
    }

    const int srow = t >> 2;
    const int sslot = (t & 3) ^ ((srow >> 1) & 3);
    const ushort_t* ga = A + (size_t)(mb * 128 + srow) * K + sslot * 8;
    const ushort_t* gb = Bt + (size_t)(nb * 128 + srow) * K + sslot * 8;
    const size_t rowskip = (size_t)64 * K;
    ushort_t* lA0 = As + wave * 512;
    ushort_t* lA1 = As + 2048 + wave * 512;
    ushort_t* lB0 = Bs + wave * 512;
    ushort_t* lB1 = Bs + 2048 + wave * 512;

    f32x4 acc[4][4] = {};

    const int kiters = K >> 5;
    for (int kt = 0; kt < kiters; ++kt) {
        gload16(ga, lA0);
        gload16(ga + rowskip, lA1);
        gload16(gb, lB0);
        gload16(gb + rowskip, lB1);
        __syncthreads();
        bf16x8 af[4], bvv[4];
#pragma unroll
        for (int i = 0; i < 4; ++i) af[i] = *(const bf16x8*)(As + aoffe[i]);
#pragma unroll
        for (int i = 0; i < 4; ++i) bvv[i] = *(const bf16x8*)(Bs + boffe[i]);
#pragma unroll
        for (int mi = 0; mi < 4; ++mi)
#pragma unroll
            for (int ni = 0; ni < 4; ++ni)
                acc[mi][ni] = __builtin_amdgcn_mfma_f32_16x16x32_bf16(af[mi], bvv[ni], acc[mi][ni], 0, 0, 0);
        __syncthreads();
        ga += 32; gb += 32;
    }

#pragma unroll
    for (int mi = 0; mi < 4; ++mi) {
        const int row0 = mb * 128 + wrow + mi * 16 + fk * 4;
#pragma unroll
        for (int ni = 0; ni < 4; ++ni) {
            const int col = nb * 128 + wcol + ni * 16 + fr;
            float bias = (EPI == 0) ? epi_vec[col] : 0.f;
            f32x4 v = acc[mi][ni];
#pragma unroll
            for (int j = 0; j < 4; ++j) {
                int row = row0 + j;
                float x = v[j];
                if (EPI == 0)      x = fmaxf(x + bias, 0.f);
                else if (EPI == 1) x = __expf(x);
                else               x = x * epi_vec[row];
                C[(size_t)row * N + col] = f2bf(x);
            }
        }
    }
}

// fp32 -> bf16 flat convert (4 floats/thread)
__global__ __launch_bounds__(256) void convert_x_k(const float* __restrict__ in,
                                                   ushort_t* __restrict__ out)
{
    size_t i = ((size_t)blockIdx.x * 256 + threadIdx.x) * 4;
    float4 v = *(const float4*)(in + i);
    us4 o;
    o[0] = f2bf(v.x); o[1] = f2bf(v.y); o[2] = f2bf(v.z); o[3] = f2bf(v.w);
    *(us4*)(out + i) = o;
}

// bf16 batched transpose: in (Z,R,C) -> out (Z,C,R)
__global__ void transpose_bf16_k(const ushort_t* __restrict__ in, ushort_t* __restrict__ out,
                                 int R, int C)
{
    __shared__ ushort_t tile[32][33];
    size_t bo = (size_t)blockIdx.z * R * C;
    const ushort_t* pin = in + bo;
    ushort_t* pout = out + bo;
    int c0 = blockIdx.x << 5, r0 = blockIdx.y << 5;
    int tx = threadIdx.x, ty = threadIdx.y;    // (32,8)
#pragma unroll
    for (int i = 0; i < 4; ++i)
        tile[ty + i * 8][tx] = pin[(size_t)(r0 + ty + i * 8) * C + c0 + tx];
    __syncthreads();
#pragma unroll
    for (int i = 0; i < 4; ++i)
        pout[(size_t)(c0 + ty + i * 8) * R + r0 + tx] = tile[tx][ty + i * 8];
}

// in-place transpose of a 4096x4096 bf16 matrix via 32x32 tile-pair swap
__global__ void transpose_inplace_k(ushort_t* __restrict__ Mx)
{
    int bi = blockIdx.y, bj = blockIdx.x;      // 128x128 tiles
    if (bi > bj) return;
    __shared__ ushort_t ta[32][33], tb[32][33];
    int r0 = bi << 5, c0 = bj << 5;
    int tx = threadIdx.x, ty = threadIdx.y;    // (32,8)
#pragma unroll
    for (int i = 0; i < 4; ++i)
        ta[ty + i * 8][tx] = Mx[(size_t)(r0 + ty + i * 8) * 4096 + c0 + tx];
    if (bi < bj) {
#pragma unroll
        for (int i = 0; i < 4; ++i)
            tb[ty + i * 8][tx] = Mx[(size_t)(c0 + ty + i * 8) * 4096 + r0 + tx];
    }
    __syncthreads();
#pragma unroll
    for (int i = 0; i < 4; ++i)
        Mx[(size_t)(c0 + ty + i * 8) * 4096 + r0 + tx] = ta[tx][ty + i * 8];
    if (bi < bj) {
#pragma unroll
        for (int i = 0; i < 4; ++i)
            Mx[(size_t)(r0 + ty + i * 8) * 4096 + c0 + tx] = tb[tx][ty + i * 8];
    }
}

// weight convert+transpose: in fp32 (R,C) -> out bf16 (C,R)
__global__ void wt_transpose_k(const float* __restrict__ in, ushort_t* __restrict__ out,
                               int R, int C)
{
    __shared__ ushort_t tile[32][33];
    int c0 = blockIdx.x << 5, r0 = blockIdx.y << 5;
    int tx = threadIdx.x, ty = threadIdx.y;    // (32,8)
#pragma unroll
    for (int i = 0; i < 4; ++i)
        tile[ty + i * 8][tx] = f2bf(in[(size_t)(r0 + ty + i * 8) * C + c0 + tx]);
    __syncthreads();
#pragma unroll
    for (int i = 0; i < 4; ++i)
        out[(size_t)(c0 + ty + i * 8) * R + r0 + tx] = tile[tx][ty + i * 8];
}

// recip of summed partials: out[idx] = 1 / sum_{i<16} p[i][idx]
__global__ __launch_bounds__(256) void rowrecip_k(const float* __restrict__ p,
                                                  float* __restrict__ out, int Mrows)
{
    int idx = blockIdx.x * 256 + threadIdx.x;
    float s = 0.f;
#pragma unroll
    for (int i = 0; i < 16; ++i) s += p[(size_t)i * Mrows + idx];
    out[idx] = 1.0f / s;
}

// reduce fused-colsum partials -> agg (2,4096)
__global__ __launch_bounds__(256) void agg_reduce_k(const float* __restrict__ part,
                                                    float* __restrict__ agg)
{
    int idx = blockIdx.x * 256 + threadIdx.x;  // 8192
    int g = idx >> 11, col = idx & 2047;
    int half = g >> 1, b = g & 1;
    const float* p = part + (size_t)half * 64 * 2048;
    float s = 0.f;
    for (int rr = 0; rr < 16; ++rr)
        s += p[(size_t)(b * 16 + rr) * 2048 + col] +
             p[(size_t)(32 + b * 16 + rr) * 2048 + col];
    agg[b * 4096 + half * 2048 + col] = s;
}

// h-MLP partial: part[kc][2][2048], kcs=16
__global__ __launch_bounds__(256) void h_part_k(const float* __restrict__ act,
                                                const float* __restrict__ W,
                                                float* __restrict__ part, int Kdim)
{
    int j = blockIdx.x * 256 + threadIdx.x;
    int kc = blockIdx.y;
    float a0 = 0.f, a1 = 0.f;
    int k0 = kc * 16;
#pragma unroll
    for (int i = 0; i < 16; ++i) {
        int k = k0 + i;
        float w = W[(size_t)k * 2048 + j];
        a0 += act[k] * w;
        a1 += act[Kdim + k] * w;
    }
    part[(size_t)(kc * 2 + 0) * 2048 + j] = a0;
    part[(size_t)(kc * 2 + 1) * 2048 + j] = a1;
}

__global__ __launch_bounds__(256) void h_reduce_mid_k(const float* __restrict__ part,
                                                      float* __restrict__ part2)
{
    int idx = blockIdx.x * 256 + threadIdx.x;
    int g2 = idx >> 12;
    int rrow = (idx >> 11) & 1, j = idx & 2047;
    float s = 0.f;
#pragma unroll
    for (int i = 0; i < 16; ++i)
        s += part[(size_t)(((g2 * 16 + i) * 2) + rrow) * 2048 + j];
    part2[(size_t)(g2 * 2 + rrow) * 2048 + j] = s;
}

__global__ __launch_bounds__(256) void h_reduce_k(const float* __restrict__ part2,
                                                  const float* __restrict__ bias,
                                                  float* __restrict__ out, int nkc)
{
    int idx = blockIdx.x * 256 + threadIdx.x;  // 2*2048
    int rrow = idx >> 11, j = idx & 2047;
    float s = 0.f;
    for (int kc = 0; kc < nkc; ++kc) s += part2[(size_t)(kc * 2 + rrow) * 2048 + j];
    s += bias[j];
    out[rrow * 2048 + j] = fmaxf(s, 0.f);
}

__global__ __launch_bounds__(256) void h3_k(const float* __restrict__ a2,
                                            const float* __restrict__ W,
                                            const float* __restrict__ b3,
                                            float* __restrict__ out)
{
    __shared__ float red[6][256];
    int t = threadIdx.x;
    float acc[6] = {0, 0, 0, 0, 0, 0};
    for (int k = t; k < 2048; k += 256) {
        float x0 = a2[k], x1 = a2[2048 + k];
#pragma unroll
        for (int c = 0; c < 3; ++c) {
            float w = W[k * 3 + c];
            acc[c] += x0 * w;
            acc[3 + c] += x1 * w;
        }
    }
#pragma unroll
    for (int c = 0; c < 6; ++c) red[c][t] = acc[c];
    __syncthreads();
    if (t < 6) {
        float s = 0.f;
        for (int i = 0; i < 256; ++i) s += red[t][i];
        s += b3[t < 3 ? t : t - 3];
        out[t] = fmaxf(s, 0.f);
    }
}

__global__ void diag_k(float* __restrict__ out, unsigned long long wsmb)
{
    if (threadIdx.x < 6) out[threadIdx.x] = 10000.0f + (float)wsmb;
}

// ---------------------------------------------------------------------------
// workspace layout (bytes) — ~214.7 MiB
// ---------------------------------------------------------------------------
constexpr size_t MB = 1024ull * 1024;
constexpr size_t OFF_W1T  = 0;
constexpr size_t OFF_W2T  = OFF_W1T  + 2048ull * 1024 * 2;
constexpr size_t OFF_W3T  = OFF_W2T  + 2048ull * 2048 * 2;
constexpr size_t OFF_XBF  = OFF_W3T  + 2048ull * 2048 * 2;       // 16384x1024 bf16
constexpr size_t OFF_R1   = OFF_XBF  + 16384ull * 1024 * 2;      // 64 MB
constexpr size_t OFF_R2   = OFF_R1   + 64 * MB;                  // 64 MB
constexpr size_t OFF_BETA = OFF_R2   + 64 * MB;
constexpr size_t OFF_ALPHA= OFF_BETA + 2ull * 4096 * 1024 * 2;
constexpr size_t OFF_PART = OFF_ALPHA+ 2ull * 4096 * 1024 * 2;   // 2x64x2048 fp32
constexpr size_t OFF_RS   = OFF_PART + 2ull * 128 * 2048 * 4;
constexpr size_t OFF_CS   = OFF_RS   + 4096 * 4;
constexpr size_t OFF_AGG  = OFF_CS   + 4096 * 4;
constexpr size_t OFF_ROWP = OFF_AGG  + 8192 * 4;                 // 16x4096 fp32
constexpr size_t OFF_COLP = OFF_ROWP + 16ull * 4096 * 4;         // 16x4096 fp32
constexpr size_t OFF_END  = OFF_COLP + 16ull * 4096 * 4;

extern "C" void kernel_launch(void* const* d_in, const int* in_sizes, int n_in,
                              void* d_out, int out_size, void* d_ws, size_t ws_size,
                              hipStream_t stream)
{
    const float* x1  = (const float*)d_in[0];
    const float* x2  = (const float*)d_in[1];
    const float* fW1 = (const float*)d_in[2];  const float* fb1 = (const float*)d_in[3];
    const float* fW2 = (const float*)d_in[4];  const float* fb2 = (const float*)d_in[5];
    const float* fW3 = (const float*)d_in[6];  const float* fb3 = (const float*)d_in[7];
    const float* gW1 = (const float*)d_in[8];  const float* gb1 = (const float*)d_in[9];
    const float* gW2 = (const float*)d_in[10]; const float* gb2 = (const float*)d_in[11];
    const float* gW3 = (const float*)d_in[12]; const float* gb3 = (const float*)d_in[13];
    const float* hW1 = (const float*)d_in[14]; const float* hb1 = (const float*)d_in[15];
    const float* hW2 = (const float*)d_in[16]; const float* hb2 = (const float*)d_in[17];
    const float* hW3 = (const float*)d_in[18]; const float* hb3 = (const float*)d_in[19];

    float* out = (float*)d_out;

    if (ws_size < OFF_END) {
        diag_k<<<1, 64, 0, stream>>>(out, (unsigned long long)(ws_size >> 20));
        return;
    }

    char* ws = (char*)d_ws;
    ushort_t* W1T  = (ushort_t*)(ws + OFF_W1T);
    ushort_t* W2T  = (ushort_t*)(ws + OFF_W2T);
    ushort_t* W3T  = (ushort_t*)(ws + OFF_W3T);
    ushort_t* XBF  = (ushort_t*)(ws + OFF_XBF);
    ushort_t* R1   = (ushort_t*)(ws + OFF_R1);
    ushort_t* R2   = (ushort_t*)(ws + OFF_R2);
    ushort_t* BETA = (ushort_t*)(ws + OFF_BETA);
    ushort_t* ALPHA= (ushort_t*)(ws + OFF_ALPHA);
    float* PART  = (float*)(ws + OFF_PART);
    float* RS    = (float*)(ws + OFF_RS);
    float* CS    = (float*)(ws + OFF_CS);
    float* AGG   = (float*)(ws + OFF_AGG);
    float* ROWP  = (float*)(ws + OFF_ROWP);
    float* COLP  = (float*)(ws + OFF_COLP);

    ushort_t* PING = R2;
    ushort_t* PONG = R2 + 16777216;                    // element offsets
    ushort_t* E    = R2;
    ushort_t* X1T  = R2 + 16777216;
    ushort_t* X2T  = R2 + 25165824;
    float* PARTH = (float*)(ws + OFF_R2);
    float* PART2 = (float*)(ws + OFF_R2 + 4 * MB);
    float* A1    = (float*)(ws + OFF_R2 + 6 * MB);
    float* A2    = (float*)(ws + OFF_R2 + 6 * MB + 16384);

    dim3 tb(32, 8);

    // 1) x -> bf16
    convert_x_k<<<8192, 256, 0, stream>>>(x1, XBF);
    convert_x_k<<<8192, 256, 0, stream>>>(x2, XBF + 8192ull * 1024);

    // 2) f-weights -> bf16 transposed
    wt_transpose_k<<<dim3(64, 32), tb, 0, stream>>>(fW1, W1T, 1024, 2048);
    wt_transpose_k<<<dim3(64, 64), tb, 0, stream>>>(fW2, W2T, 2048, 2048);
    wt_transpose_k<<<dim3(64, 64), tb, 0, stream>>>(fW3, W3T, 2048, 2048);

    // 3) f-MLP in 2 chunks of 8192 rows: XBF -> PING -> PONG -> F(R1)
    for (int c = 0; c < 2; ++c) {
        const ushort_t* src = XBF + (size_t)c * 8192 * 1024;
        ushort_t* dst = R1 + (size_t)c * 8192 * 2048;
        gemm256<0><<<256, 512, 0, stream>>>(src, W1T, PING, 8192, 2048, 1024, fb1, nullptr, nullptr);
        gemm256<0><<<256, 512, 0, stream>>>(PING, W2T, PONG, 8192, 2048, 2048, fb2, nullptr, nullptr);
        gemm256<0><<<256, 512, 0, stream>>>(PONG, W3T, dst, 8192, 2048, 2048, fb3, nullptr, nullptr);
    }

    // 4) x1^T -> X1T, x2^T -> X2T
    transpose_bf16_k<<<dim3(32, 128, 2), tb, 0, stream>>>(XBF, X1T, 4096, 1024);
    transpose_bf16_k<<<dim3(32, 128, 2), tb, 0, stream>>>(XBF + 8192ull * 1024, X2T, 4096, 1024);

    // 5) attention per batch: ONE score GEMM (E + rowsum + colsum partials),
    //    beta from E, in-place transpose E -> E^T, alpha from E^T.
    for (int b = 0; b < 2; ++b) {
        const ushort_t* fa  = R1 + (size_t)b * 4096 * 2048;
        const ushort_t* fbp = R1 + (size_t)(8192 + b * 4096) * 2048;
        gemm256<1><<<256, 512, 0, stream>>>(fa, fbp, E, 4096, 4096, 2048, nullptr, ROWP, COLP);
        rowrecip_k<<<16, 256, 0, stream>>>(ROWP, RS, 4096);
        rowrecip_k<<<16, 256, 0, stream>>>(COLP, CS, 4096);
        gemm_bt<2><<<256, 256, 0, stream>>>(E, X2T + (size_t)b * 1024 * 4096,
                                            BETA + (size_t)b * 4096 * 1024,
                                            4096, 1024, 4096, RS);
        transpose_inplace_k<<<dim3(128, 128), tb, 0, stream>>>(E);
        gemm_bt<2><<<256, 256, 0, stream>>>(E, X1T + (size_t)b * 1024 * 4096,
                                            ALPHA + (size_t)b * 4096 * 1024,
                                            4096, 1024, 4096, CS);
    }

    // 6) g-weights overwrite the W region
    wt_transpose_k<<<dim3(64, 32), tb, 0, stream>>>(gW1, W1T, 1024, 2048);
    wt_transpose_k<<<dim3(64, 64), tb, 0, stream>>>(gW2, W2T, 2048, 2048);
    wt_transpose_k<<<dim3(64, 64), tb, 0, stream>>>(gW3, W3T, 2048, 2048);

    // 7) g-MLP, 2 chunks of 16384 rows; L3 fuses column sums (EPI=3)
    for (int c = 0; c < 2; ++c) {
        const ushort_t* xsrc = XBF + (size_t)c * 8192 * 1024;
        const ushort_t* asrc = (c == 0) ? BETA : ALPHA;
        gemm256<0><<<256, 512, 0, stream>>>(xsrc, W1T, R1, 8192, 2048, 1024, gb1, nullptr, nullptr);
        gemm256<0><<<256, 512, 0, stream>>>(asrc, W1T, R1 + 8192ull * 2048, 8192, 2048, 1024, gb1, nullptr, nullptr);
        gemm256<0><<<512, 512, 0, stream>>>(R1, W2T, R2, 16384, 2048, 2048, gb2, nullptr, nullptr);
        gemm256<3><<<512, 512, 0, stream>>>(R2, W3T,
                                            (ushort_t*)(PART + (size_t)c * 64 * 2048),
                                            16384, 2048, 2048, gb3, nullptr, nullptr);
    }
    agg_reduce_k<<<32, 256, 0, stream>>>(PART, AGG);

    // 8) h-MLP (fp32, deterministic tree reduction; scratch in dead R2)
    h_part_k<<<dim3(8, 256), 256, 0, stream>>>(AGG, hW1, PARTH, 4096);
    h_reduce_mid_k<<<256, 256, 0, stream>>>(PARTH, PART2);
    h_reduce_k<<<16, 256, 0, stream>>>(PART2, hb1, A1, 16);
    h_part_k<<<dim3(8, 128), 256, 0, stream>>>(A1, hW2, PARTH, 2048);
    h_reduce_mid_k<<<128, 256, 0, stream>>>(PARTH, PART2);
    h_reduce_k<<<16, 256, 0, stream>>>(PART2, hb2, A2, 8);
    h3_k<<<1, 256, 0, stream>>>(A2, hW3, hb3, out);
}